// Round 7
// baseline (663.079 us; speedup 1.0000x reference)
//
#include <hip/hip_runtime.h>

typedef unsigned short ushort_t;
typedef __bf16 bf16x8 __attribute__((ext_vector_type(8)));
typedef __bf16 bf16x2 __attribute__((ext_vector_type(2)));
typedef float f32x4 __attribute__((ext_vector_type(4)));

__device__ __forceinline__ ushort_t f2bf(float f) {
    unsigned u;
    __builtin_memcpy(&u, &f, 4);
    u += 0x7fffu + ((u >> 16) & 1u);   // RNE
    return (ushort_t)(u >> 16);
}

__device__ __forceinline__ float silu(float x) {
    float e = __builtin_amdgcn_exp2f(x * -1.442695040888963f);
    return x * __builtin_amdgcn_rcpf(1.0f + e);
}

__device__ __forceinline__ float rdlane(float v, int l) {
    return __builtin_bit_cast(float, __builtin_amdgcn_readlane(__builtin_bit_cast(int, v), l));
}

// XOR-swizzled A-fragment LDS layout for 16x16x32 bf16 MFMA (verified R3-R6):
// element (row,k) -> frag  = frag_base + (k>>5)                          [1 KB]
//                    slot  = ((row&15) ^ ((k>>5)&3) ^ (((k>>3)&3)<<2))
//                            + 16*((k>>3)&3)                             [16 B]
//                    byte  = (k&7)*2
// Reads: b128, 64 distinct slots, conflict-free. Writes: 2-way (free).

// Packed scatter accumulator: one f64 atomic carries sum + 65536*count.
#define CNT_UNIT 65536.0

// Session notes:
//  R5: __launch_bounds__(512,4) -> 64-VGPR cap -> acc spills -> FETCH 3.5 GB, 2.9x slower.
//  R6: 512-thr/64KB blocks do NOT co-reside (occupancy stuck ~22%); 256-thr blocks do.
//  => 256-thr blocks, shrink LDS to 48 KB so 3 blocks/CU can co-reside.
__global__ __launch_bounds__(256, 4) void mlp_kernel(
    const float* __restrict__ v,    // [N,3] f32
    const float* __restrict__ rij,  // [E,3] f32
    const float* __restrict__ W0,   // [128,4]
    const float* __restrict__ b0,   // [128]
    const float* __restrict__ W1,   // [128,128] (n,k)
    const float* __restrict__ b1,   // [128]
    const float* __restrict__ W2,   // [128]
    const float* __restrict__ b2,   // [1]
    const int* __restrict__ eidx,   // [2,E] int32
    double* __restrict__ acc_i, double* __restrict__ acc_j,
    int E, int nchunks)
{
    __shared__ ushort_t sW1[16384];   // 32 KB, frag layout (unswizzled)
    __shared__ ushort_t sH0[8192];    // 16 KB, XOR-swizzled; wave w owns frags [4w,4w+4)

    const int tid  = threadIdx.x;
    const int lane = tid & 63;
    const int wave = tid >> 6;        // 0..3

    // ---- stage W1 (f32 -> bf16) into LDS (once per block, 256 threads) ----
    {
        int n = tid >> 1, half = tid & 1;
        const float* src = W1 + n * 128;
#pragma unroll
        for (int dk = 0; dk < 8; dk++) {
            int k0   = half * 64 + dk * 8;
            int frag = (n >> 4) * 4 + (k0 >> 5);
            int slot = (n & 15) + 16 * ((k0 >> 3) & 3);
            ushort_t tmp[8];
#pragma unroll
            for (int t = 0; t < 8; t++) tmp[t] = f2bf(src[k0 + t]);
            *(uint4*)(&sW1[frag * 512 + slot * 8]) = *(const uint4*)tmp;
        }
    }

    // ---- per-lane constants ----
    float4 w0q[2]; float b0v[2];
#pragma unroll
    for (int kk = 0; kk < 2; kk++) {
        int h = 2 * lane + kk;
        w0q[kk].x = W0[h * 4 + 0];
        w0q[kk].y = W0[h * 4 + 1];
        w0q[kk].z = W0[h * 4 + 2];
        w0q[kk].w = W0[h * 4 + 3];
        b0v[kk]   = b0[h];
    }
    float b1v[8], w2v[8];
#pragma unroll
    for (int nt = 0; nt < 8; nt++) {
        int ccol = nt * 16 + (lane & 15);
        b1v[nt] = b1[ccol];
        w2v[nt] = W2[ccol];
    }
    const float b2f = b2[0];

    __syncthreads();   // sW1 ready; hot loop below is barrier-free

    const int q = lane >> 4, c = lane & 15, p = (lane >> 2) & 3, bsub = lane & 3;
    const int ple  = lane >> 2;     // edge-in-wave this lane preloads (lanes 0..31)
    const int comp = lane & 3;      // 0..2: v component, 3: |r|/H

    // ---- gather preload for one chunk (lane-parallel, lanes 0..31) ----
    auto preload = [&](int ch, float& val_o, int& idx_o) {
        float val = 0.f; int idxr = 0;
        if (ch < nchunks && lane < 32) {
            int pe = ch * 32 + wave * 8 + ple;
            if (pe < E) {
                if (comp == 3) {
                    float r0 = rij[3 * pe], r1 = rij[3 * pe + 1], r2 = rij[3 * pe + 2];
                    val = sqrtf(fmaf(r0, r0, fmaf(r1, r1, r2 * r2))) * (1.0f / 3.0f);
                } else {
                    int i = eidx[pe], jj = eidx[E + pe];
                    idxr = (comp == 1) ? jj : i;
                    val = v[3 * i + comp] - v[3 * jj + comp];
                }
            }
        }
        val_o = val; idx_o = idxr;
    };

    float val; int idxr;
    preload(blockIdx.x, val, idxr);   // prologue load for first chunk

    for (int chunk = blockIdx.x; chunk < nchunks; chunk += gridDim.x) {
        const float val_cur = val;
        const int   idx_cur = idxr;
        // issue next chunk's gathers now; consumed one full iteration later
        preload(chunk + (int)gridDim.x, val, idxr);

        const int ebase = chunk * 32 + wave * 8;

        // ===== phase A: layer0 -> swizzled bf16 H0 (wave's 16 rows) =====
#pragma unroll
        for (int le = 0; le < 8; le++) {
            float vx = rdlane(val_cur, le * 4 + 0);
            float vy = rdlane(val_cur, le * 4 + 1);
            float vz = rdlane(val_cur, le * 4 + 2);
            float rr = rdlane(val_cur, le * 4 + 3);
            float si[2], sj[2];
#pragma unroll
            for (int kk = 0; kk < 2; kk++) {
                float cc = fmaf(w0q[kk].x, rr, b0v[kk]);
                float dd = fmaf(w0q[kk].y, vx, fmaf(w0q[kk].z, vy, w0q[kk].w * vz));
                si[kk] = silu(cc + dd);
                sj[kk] = silu(cc - dd);
            }
            bf16x2 pki, pkj;
            pki[0] = (__bf16)si[0]; pki[1] = (__bf16)si[1];
            pkj[0] = (__bf16)sj[0]; pkj[1] = (__bf16)sj[1];
            int mi = 2 * le;                       // x_i row; x_j row = mi+1
            int fr   = wave * 4 + q;               // same k-frag for both rows
            int sl_i = ((mi ^ q ^ (p << 2)) & 15) + (p << 4);
            int sl_j = (((mi + 1) ^ q ^ (p << 2)) & 15) + (p << 4);
            ((unsigned*)sH0)[fr * 256 + sl_i * 4 + bsub] = __builtin_bit_cast(unsigned, pki);
            ((unsigned*)sH0)[fr * 256 + sl_j * 4 + bsub] = __builtin_bit_cast(unsigned, pkj);
        }

        // ===== GEMM: h1_pre = H0 @ W1^T + b1 (acc pre-init with b1) =====
        f32x4 acc[8];
#pragma unroll
        for (int nt = 0; nt < 8; nt++)
            acc[nt] = (f32x4){b1v[nt], b1v[nt], b1v[nt], b1v[nt]};

#pragma unroll
        for (int ks = 0; ks < 4; ks++) {
            int sl_rd = (((lane & 15) ^ ks ^ (q << 2)) & 15) + 16 * q;
            bf16x8 a0 = *(const bf16x8*)(&sH0[(wave * 4 + ks) * 512 + sl_rd * 8]);
#pragma unroll
            for (int nt = 0; nt < 8; nt++) {
                bf16x8 bb = *(const bf16x8*)(&sW1[(nt * 4 + ks) * 512 + lane * 8]);
                acc[nt] = __builtin_amdgcn_mfma_f32_16x16x32_bf16(a0, bb, acc[nt], 0, 0, 0);
            }
        }

        // ===== epilogue: silu(h1) . W2 -> +b2 -> packed f64 scatter-add =====
        float rs[4] = {0.f, 0.f, 0.f, 0.f};
#pragma unroll
        for (int nt = 0; nt < 8; nt++)
#pragma unroll
            for (int r = 0; r < 4; r++)
                rs[r] = fmaf(silu(acc[nt][r]), w2v[nt], rs[r]);

#pragma unroll
        for (int r = 0; r < 4; r++) {
            float s = rs[r];
            s += __shfl_xor(s, 1, 64);
            s += __shfl_xor(s, 2, 64);
            s += __shfl_xor(s, 4, 64);
            s += __shfl_xor(s, 8, 64);
            int el  = q * 2 + (r >> 1);            // edge within wave's 8
            int src = el * 4 + (r & 1);            // comp0 lane holds i, comp1 holds j
            int node = __shfl(idx_cur, src, 64);
            int e = ebase + el;
            if (c == 0 && e < E) {
                double contrib = (double)(s + b2f) + CNT_UNIT;
                if (r & 1) atomicAdd(&acc_j[node], contrib);
                else       atomicAdd(&acc_i[node], contrib);
            }
        }
        // wave-local LDS WAR across chunks is safe: one wave's DS ops are in-order.
    }
}

__global__ void finalize_kernel(const double* __restrict__ acc_i,
                                const double* __restrict__ acc_j,
                                float* __restrict__ out, int N)
{
    int n = blockIdx.x * 256 + threadIdx.x;
    if (n < N) {
        double ti = acc_i[n], tj = acc_j[n];
        double ci = rint(ti * (1.0 / CNT_UNIT));
        double cj = rint(tj * (1.0 / CNT_UNIT));
        double si = ti - ci * CNT_UNIT;
        double sj = tj - cj * CNT_UNIT;
        out[n] = (float)(si / fmax(ci, 1.0) + sj / fmax(cj, 1.0));
    }
}

extern "C" void kernel_launch(void* const* d_in, const int* in_sizes, int n_in,
                              void* d_out, int out_size, void* d_ws, size_t ws_size,
                              hipStream_t stream) {
    const float* v   = (const float*)d_in[0];
    const float* rij = (const float*)d_in[1];
    const float* W0  = (const float*)d_in[2];
    const float* b0  = (const float*)d_in[3];
    const float* W1  = (const float*)d_in[4];
    const float* b1  = (const float*)d_in[5];
    const float* W2  = (const float*)d_in[6];
    const float* b2  = (const float*)d_in[7];
    const int* eidx  = (const int*)d_in[8];

    const int E = in_sizes[1] / 3;
    const int N = out_size;

    double* acc_i = (double*)d_ws;
    double* acc_j = acc_i + N;

    hipMemsetAsync(d_ws, 0, (size_t)2 * N * sizeof(double), stream);

    int nchunks = (E + 31) / 32;
    int grid = nchunks < 768 ? nchunks : 768;
    mlp_kernel<<<grid, 256, 0, stream>>>(v, rij, W0, b0, W1, b1, W2, b2, eidx,
                                         acc_i, acc_j, E, nchunks);
    finalize_kernel<<<(N + 255) / 256, 256, 0, stream>>>(acc_i, acc_j,
                                                         (float*)d_out, N);
}

// Round 8
// 433.776 us; speedup vs baseline: 1.5286x; 1.5286x over previous
//
#include <hip/hip_runtime.h>

typedef unsigned short ushort_t;
typedef __bf16 bf16x8 __attribute__((ext_vector_type(8)));
typedef __bf16 bf16x2 __attribute__((ext_vector_type(2)));
typedef float f32x4 __attribute__((ext_vector_type(4)));

__device__ __forceinline__ ushort_t f2bf(float f) {
    unsigned u;
    __builtin_memcpy(&u, &f, 4);
    u += 0x7fffu + ((u >> 16) & 1u);   // RNE
    return (ushort_t)(u >> 16);
}

__device__ __forceinline__ float silu(float x) {
    float e = __builtin_amdgcn_exp2f(x * -1.442695040888963f);
    return x * __builtin_amdgcn_rcpf(1.0f + e);
}

__device__ __forceinline__ float rdlane(float v, int l) {
    return __builtin_bit_cast(float, __builtin_amdgcn_readlane(__builtin_bit_cast(int, v), l));
}

// XOR-swizzled A-fragment LDS layout for 16x16x32 bf16 MFMA (verified R3-R7):
// element (row,k) -> frag  = frag_base + (k>>5)                          [1 KB]
//                    slot  = ((row&15) ^ ((k>>5)&3) ^ (((k>>3)&3)<<2))
//                            + 16*((k>>3)&3)                             [16 B]
//                    byte  = (k&7)*2
// Reads: b128, 64 distinct slots, conflict-free. Writes: 2-way (free).

// Packed scatter accumulator: one f64 atomic carries sum + 65536*count.
#define CNT_UNIT 65536.0

// Session notes:
//  R5: __launch_bounds__(512,4) -> 64-VGPR cap -> acc spills -> FETCH 3.5 GB.
//  R6: 512-thr/64KB blocks do NOT co-reside; 256-thr blocks do.
//  R7: __launch_bounds__(256,4) infeasible -> bound dropped -> VGPR 148 (>128
//      bucket) -> occupancy collapsed to ~1 block/CU. Same VALU work, worse density.
//  R8: R4 structure (16 edges/wave, VGPR 104 proven), sH0 halved via two-pass
//      phase A with A-fragments held in registers -> 48 KB block LDS, grid 768.
__global__ __launch_bounds__(256, 2) void mlp_kernel(
    const float* __restrict__ v,    // [N,3] f32
    const float* __restrict__ rij,  // [E,3] f32
    const float* __restrict__ W0,   // [128,4]
    const float* __restrict__ b0,   // [128]
    const float* __restrict__ W1,   // [128,128] (n,k)
    const float* __restrict__ b1,   // [128]
    const float* __restrict__ W2,   // [128]
    const float* __restrict__ b2,   // [1]
    const int* __restrict__ eidx,   // [2,E] int32
    double* __restrict__ acc_i, double* __restrict__ acc_j,
    int E, int nchunks)
{
    __shared__ ushort_t sW1[16384];   // 32 KB, frag layout (unswizzled)
    __shared__ ushort_t sH0[8192];    // 16 KB; wave w owns 2048 ushorts, reused 2x/chunk

    const int tid  = threadIdx.x;
    const int lane = tid & 63;
    const int wave = tid >> 6;        // 0..3

    // ---- stage W1 (f32 -> bf16) into LDS (once per block, 256 threads) ----
    {
        int n = tid >> 1, half = tid & 1;
        const float* src = W1 + n * 128;
#pragma unroll
        for (int dk = 0; dk < 8; dk++) {
            int k0   = half * 64 + dk * 8;
            int frag = (n >> 4) * 4 + (k0 >> 5);
            int slot = (n & 15) + 16 * ((k0 >> 3) & 3);
            ushort_t tmp[8];
#pragma unroll
            for (int t = 0; t < 8; t++) tmp[t] = f2bf(src[k0 + t]);
            *(uint4*)(&sW1[frag * 512 + slot * 8]) = *(const uint4*)tmp;
        }
    }

    // ---- per-lane constants ----
    float4 w0q[2]; float b0v[2];
#pragma unroll
    for (int kk = 0; kk < 2; kk++) {
        int h = 2 * lane + kk;
        w0q[kk].x = W0[h * 4 + 0];
        w0q[kk].y = W0[h * 4 + 1];
        w0q[kk].z = W0[h * 4 + 2];
        w0q[kk].w = W0[h * 4 + 3];
        b0v[kk]   = b0[h];
    }
    float b1v[8], w2v[8];
#pragma unroll
    for (int nt = 0; nt < 8; nt++) {
        int ccol = nt * 16 + (lane & 15);
        b1v[nt] = b1[ccol];
        w2v[nt] = W2[ccol];
    }
    const float b2f = b2[0];

    __syncthreads();   // sW1 ready; hot loop below is barrier-free

    const int q = lane >> 4, c = lane & 15, p = (lane >> 2) & 3, bsub = lane & 3;
    const int ple  = lane >> 2;     // edge-in-wave this lane preloads (0..15)
    const int comp = lane & 3;      // 0..2: v component, 3: |r|/H

    // ---- gather preload for one chunk (lane-parallel) ----
    auto preload = [&](int ch, float& val_o, int& idx_o) {
        float val = 0.f; int idxr = 0;
        int pe = ch * 64 + wave * 16 + ple;
        if (ch < nchunks && pe < E) {
            if (comp == 3) {
                float r0 = rij[3 * pe], r1 = rij[3 * pe + 1], r2 = rij[3 * pe + 2];
                val = sqrtf(fmaf(r0, r0, fmaf(r1, r1, r2 * r2))) * (1.0f / 3.0f);
            } else {
                int i = eidx[pe], jj = eidx[E + pe];
                idxr = (comp == 1) ? jj : i;
                val = v[3 * i + comp] - v[3 * jj + comp];
            }
        }
        val_o = val; idx_o = idxr;
    };

    float val; int idxr;
    preload(blockIdx.x, val, idxr);   // prologue load for first chunk

    for (int chunk = blockIdx.x; chunk < nchunks; chunk += gridDim.x) {
        const float val_cur = val;
        const int   idx_cur = idxr;
        // issue next chunk's gathers now; consumed one full iteration later
        preload(chunk + (int)gridDim.x, val, idxr);

        const int ebase = chunk * 64 + wave * 16;

        // ===== phase A (two passes): layer0 -> 4KB wave slab -> A-frags in regs =====
        bf16x8 afr[2][4];
#pragma unroll
        for (int pp = 0; pp < 2; pp++) {
#pragma unroll
            for (int le2 = 0; le2 < 8; le2++) {
                int le = pp * 8 + le2;
                float vx = rdlane(val_cur, le * 4 + 0);
                float vy = rdlane(val_cur, le * 4 + 1);
                float vz = rdlane(val_cur, le * 4 + 2);
                float rr = rdlane(val_cur, le * 4 + 3);
                float si[2], sj[2];
#pragma unroll
                for (int kk = 0; kk < 2; kk++) {
                    float cc = fmaf(w0q[kk].x, rr, b0v[kk]);
                    float dd = fmaf(w0q[kk].y, vx, fmaf(w0q[kk].z, vy, w0q[kk].w * vz));
                    si[kk] = silu(cc + dd);
                    sj[kk] = silu(cc - dd);
                }
                bf16x2 pki, pkj;
                pki[0] = (__bf16)si[0]; pki[1] = (__bf16)si[1];
                pkj[0] = (__bf16)sj[0]; pkj[1] = (__bf16)sj[1];
                int mi = 2 * le2;                  // local row in this 16-row tile
                int sl_i = ((mi ^ q ^ (p << 2)) & 15) + (p << 4);
                int sl_j = (((mi + 1) ^ q ^ (p << 2)) & 15) + (p << 4);
                ((unsigned*)sH0)[wave * 1024 + q * 256 + sl_i * 4 + bsub] = __builtin_bit_cast(unsigned, pki);
                ((unsigned*)sH0)[wave * 1024 + q * 256 + sl_j * 4 + bsub] = __builtin_bit_cast(unsigned, pkj);
            }
            // pull this tile's A-fragments into registers (wave-internal DS order
            // guarantees the reads see this pass's writes; next pass may then
            // safely overwrite the slab)
#pragma unroll
            for (int ks = 0; ks < 4; ks++) {
                int sl_rd = (((lane & 15) ^ ks ^ (q << 2)) & 15) + 16 * q;
                afr[pp][ks] = *(const bf16x8*)(&sH0[wave * 2048 + ks * 512 + sl_rd * 8]);
            }
        }

        // ===== GEMM: h1_pre = H0 @ W1^T + b1 (A from regs, B from LDS) =====
        f32x4 acc[2][8];
#pragma unroll
        for (int t = 0; t < 2; t++)
#pragma unroll
            for (int nt = 0; nt < 8; nt++)
                acc[t][nt] = (f32x4){b1v[nt], b1v[nt], b1v[nt], b1v[nt]};

#pragma unroll
        for (int ks = 0; ks < 4; ks++) {
#pragma unroll
            for (int nt = 0; nt < 8; nt++) {
                bf16x8 bb = *(const bf16x8*)(&sW1[(nt * 4 + ks) * 512 + lane * 8]);
                acc[0][nt] = __builtin_amdgcn_mfma_f32_16x16x32_bf16(afr[0][ks], bb, acc[0][nt], 0, 0, 0);
                acc[1][nt] = __builtin_amdgcn_mfma_f32_16x16x32_bf16(afr[1][ks], bb, acc[1][nt], 0, 0, 0);
            }
        }

        // ===== epilogue: silu(h1) . W2 -> +b2 -> packed f64 scatter-add =====
        float rs[2][4] = {{0.f, 0.f, 0.f, 0.f}, {0.f, 0.f, 0.f, 0.f}};
#pragma unroll
        for (int t = 0; t < 2; t++)
#pragma unroll
            for (int nt = 0; nt < 8; nt++)
#pragma unroll
                for (int r = 0; r < 4; r++)
                    rs[t][r] = fmaf(silu(acc[t][nt][r]), w2v[nt], rs[t][r]);

#pragma unroll
        for (int t = 0; t < 2; t++)
#pragma unroll
            for (int r = 0; r < 4; r++) {
                float s = rs[t][r];
                s += __shfl_xor(s, 1, 64);
                s += __shfl_xor(s, 2, 64);
                s += __shfl_xor(s, 4, 64);
                s += __shfl_xor(s, 8, 64);
                int el  = t * 8 + q * 2 + (r >> 1);    // edge within wave's 16
                int src = el * 4 + (r & 1);            // comp0 lane holds i, comp1 holds j
                int node = __shfl(idx_cur, src, 64);
                int e = ebase + el;
                if (c == 0 && e < E) {
                    double contrib = (double)(s + b2f) + CNT_UNIT;
                    if (r & 1) atomicAdd(&acc_j[node], contrib);
                    else       atomicAdd(&acc_i[node], contrib);
                }
            }
        // wave-local LDS WAR across chunks is safe: one wave's DS ops are in-order.
    }
}

__global__ void finalize_kernel(const double* __restrict__ acc_i,
                                const double* __restrict__ acc_j,
                                float* __restrict__ out, int N)
{
    int n = blockIdx.x * 256 + threadIdx.x;
    if (n < N) {
        double ti = acc_i[n], tj = acc_j[n];
        double ci = rint(ti * (1.0 / CNT_UNIT));
        double cj = rint(tj * (1.0 / CNT_UNIT));
        double si = ti - ci * CNT_UNIT;
        double sj = tj - cj * CNT_UNIT;
        out[n] = (float)(si / fmax(ci, 1.0) + sj / fmax(cj, 1.0));
    }
}

extern "C" void kernel_launch(void* const* d_in, const int* in_sizes, int n_in,
                              void* d_out, int out_size, void* d_ws, size_t ws_size,
                              hipStream_t stream) {
    const float* v   = (const float*)d_in[0];
    const float* rij = (const float*)d_in[1];
    const float* W0  = (const float*)d_in[2];
    const float* b0  = (const float*)d_in[3];
    const float* W1  = (const float*)d_in[4];
    const float* b1  = (const float*)d_in[5];
    const float* W2  = (const float*)d_in[6];
    const float* b2  = (const float*)d_in[7];
    const int* eidx  = (const int*)d_in[8];

    const int E = in_sizes[1] / 3;
    const int N = out_size;

    double* acc_i = (double*)d_ws;
    double* acc_j = acc_i + N;

    hipMemsetAsync(d_ws, 0, (size_t)2 * N * sizeof(double), stream);

    int nchunks = (E + 63) / 64;
    int grid = nchunks < 768 ? nchunks : 768;
    mlp_kernel<<<grid, 256, 0, stream>>>(v, rij, W0, b0, W1, b1, W2, b2, eidx,
                                         acc_i, acc_j, E, nchunks);
    finalize_kernel<<<(N + 255) / 256, 256, 0, stream>>>(acc_i, acc_j,
                                                         (float*)d_out, N);
}